// Round 4
// baseline (89.000 us; speedup 1.0000x reference)
//
#include <hip/hip_runtime.h>

#define Bn 1024
#define Dn 512
#define Cn 512

typedef __attribute__((ext_vector_type(8))) short s16x8;   // 8 bf16 = 4 VGPR (MFMA A/B frag)
typedef __attribute__((ext_vector_type(4))) float f32x4;   // MFMA C/D frag
typedef __attribute__((ext_vector_type(4))) unsigned short u16x4;
typedef __attribute__((ext_vector_type(8))) unsigned short u16x8;

__device__ __forceinline__ unsigned short f2bf(float f) {  // RNE f32->bf16
    unsigned u = __builtin_bit_cast(unsigned, f);
    u += 0x7FFF + ((u >> 16) & 1);
    return (unsigned short)(u >> 16);
}

__device__ __forceinline__ float waveSum(float v) {
    #pragma unroll
    for (int off = 32; off > 0; off >>= 1) v += __shfl_xor(v, off, 64);
    return v;
}

// bid < 256: x fp32 -> bf16 (row-major). bid >= 256: W[k][c] -> Wt[c][k] bf16 via LDS tile.
__global__ __launch_bounds__(256) void conv_kernel(const float* __restrict__ x,
                                                   const float* __restrict__ W,
                                                   unsigned short* __restrict__ xb,
                                                   unsigned short* __restrict__ wt)
{
    const int tid = threadIdx.x;
    if (blockIdx.x < 256) {
        const int base = (blockIdx.x * 256 + tid) * 8;
        float4 v0 = *(const float4*)&x[base];
        float4 v1 = *(const float4*)&x[base + 4];
        u16x8 o;
        o[0] = f2bf(v0.x); o[1] = f2bf(v0.y); o[2] = f2bf(v0.z); o[3] = f2bf(v0.w);
        o[4] = f2bf(v1.x); o[5] = f2bf(v1.y); o[6] = f2bf(v1.z); o[7] = f2bf(v1.w);
        *(u16x8*)&xb[base] = o;
    } else {
        __shared__ unsigned short lt[64][73];   // [c_local][k_local], odd pad: 2-way max
        const int tb = blockIdx.x - 256;        // 8x8 tiles of 64x64
        const int k0 = (tb >> 3) * 64, c0 = (tb & 7) * 64;
        const int rr = tid >> 4, cc = tid & 15;
        #pragma unroll
        for (int p = 0; p < 4; ++p) {
            const int kl = rr + p * 16;
            float4 v = *(const float4*)&W[(size_t)(k0 + kl) * Cn + c0 + cc * 4];
            lt[cc * 4 + 0][kl] = f2bf(v.x);
            lt[cc * 4 + 1][kl] = f2bf(v.y);
            lt[cc * 4 + 2][kl] = f2bf(v.z);
            lt[cc * 4 + 3][kl] = f2bf(v.w);
        }
        __syncthreads();
        #pragma unroll
        for (int p = 0; p < 4; ++p) {
            const int cl = rr + p * 16;
            u16x4 o;
            o[0] = lt[cl][cc * 4 + 0]; o[1] = lt[cl][cc * 4 + 1];
            o[2] = lt[cl][cc * 4 + 2]; o[3] = lt[cl][cc * 4 + 3];
            *(u16x4*)&wt[(size_t)(c0 + cl) * Dn + k0 + cc * 4] = o;
        }
    }
}

// grid=64, block=1024. Block: 16 samples x full 512 cols. Wave wv: cols [wv*32, wv*32+32).
__global__ __launch_bounds__(1024) void gnorm_mfma(
    const unsigned short* __restrict__ xb,   // [B][D] bf16
    const unsigned short* __restrict__ wt,   // [C][D] bf16 (= W^T)
    const float* __restrict__ x,             // fp32, for ||x||^2
    const float* __restrict__ y,             // [B][C]
    const float* __restrict__ bias,          // [C]
    float* __restrict__ out)                 // [B]
{
    __shared__ float lmax[16][16];   // [row][wave]
    __shared__ float lsum[16][16];
    __shared__ float lgsq[16][16];
    __shared__ float xn2s[16];

    const int tid = threadIdx.x;
    const int wv  = tid >> 6;
    const int l   = tid & 63;
    const int l15 = l & 15;
    const int lg  = l >> 4;          // 0..3 (k-octet group / row-quad group)
    const int s0  = blockIdx.x * 16;

    // ||x_row||^2 — wave wv owns row wv (fp32 path, exact)
    {
        const float* xr = &x[(size_t)(s0 + wv) * Dn + l * 8];
        float4 a = *(const float4*)xr;
        float4 b = *(const float4*)(xr + 4);
        float ss = a.x*a.x + a.y*a.y + a.z*a.z + a.w*a.w
                 + b.x*b.x + b.y*b.y + b.z*b.z + b.w*b.w;
        ss = waveSum(ss);
        if (l == 0) xn2s[wv] = ss;
    }

    // GEMM: z[16 x 32] per wave via mfma_f32_16x16x32_bf16, K=512 in 16 steps.
    // A frag: lane holds x[s0 + (l&15)][k0 + (l>>4)*8 + j], j=0..7 (16B contiguous)
    // B frag: lane holds Wt[c][k0 + (l>>4)*8 + j] (16B contiguous) — m97 B^T pattern
    f32x4 acc0 = {0.f, 0.f, 0.f, 0.f}, acc1 = {0.f, 0.f, 0.f, 0.f};
    const unsigned short* ap  = &xb[(size_t)(s0 + l15) * Dn + lg * 8];
    const unsigned short* bp0 = &wt[(size_t)(wv * 32 + l15) * Dn + lg * 8];
    const unsigned short* bp1 = bp0 + 16 * Dn;
    #pragma unroll
    for (int ks = 0; ks < 16; ++ks) {
        s16x8 a  = *(const s16x8*)(ap  + ks * 32);
        s16x8 b0 = *(const s16x8*)(bp0 + ks * 32);
        s16x8 b1 = *(const s16x8*)(bp1 + ks * 32);
        acc0 = __builtin_amdgcn_mfma_f32_16x16x32_bf16(a, b0, acc0, 0, 0, 0);
        acc1 = __builtin_amdgcn_mfma_f32_16x16x32_bf16(a, b1, acc1, 0, 0, 0);
    }

    // Epilogue. C/D layout (verified): col = l&15, row = (l>>4)*4 + reg.
    const int c0 = wv * 32 + l15;
    const int c1 = c0 + 16;
    const float b0v = bias[c0], b1v = bias[c1];
    float z0[4], z1[4];
    #pragma unroll
    for (int r = 0; r < 4; ++r) { z0[r] = acc0[r] + b0v; z1[r] = acc1[r] + b1v; }

    // per-row max over this wave's 32 cols (reduce across the 16-lane col group)
    #pragma unroll
    for (int r = 0; r < 4; ++r) {
        float vm = fmaxf(z0[r], z1[r]);
        #pragma unroll
        for (int off = 1; off < 16; off <<= 1) vm = fmaxf(vm, __shfl_xor(vm, off, 64));
        if (l15 == 0) lmax[lg * 4 + r][wv] = vm;
    }
    __syncthreads();
    float mfin[4];
    #pragma unroll
    for (int r = 0; r < 4; ++r) {
        float vm = lmax[lg * 4 + r][0];
        #pragma unroll
        for (int w = 1; w < 16; ++w) vm = fmaxf(vm, lmax[lg * 4 + r][w]);
        mfin[r] = vm;
    }

    // sum of exp
    float e0[4], e1[4];
    #pragma unroll
    for (int r = 0; r < 4; ++r) {
        e0[r] = __expf(z0[r] - mfin[r]);
        e1[r] = __expf(z1[r] - mfin[r]);
        float sv = e0[r] + e1[r];
        #pragma unroll
        for (int off = 1; off < 16; off <<= 1) sv += __shfl_xor(sv, off, 64);
        if (l15 == 0) lsum[lg * 4 + r][wv] = sv;
    }
    __syncthreads();

    // ||g||^2 partials
    #pragma unroll
    for (int r = 0; r < 4; ++r) {
        const int m = lg * 4 + r;
        float dv = 0.f;
        #pragma unroll
        for (int w = 0; w < 16; ++w) dv += lsum[m][w];
        const float inv = 1.0f / dv;
        float g0 = e0[r] * inv - y[(size_t)(s0 + m) * Cn + c0];
        float g1 = e1[r] * inv - y[(size_t)(s0 + m) * Cn + c1];
        float gs = g0 * g0 + g1 * g1;
        #pragma unroll
        for (int off = 1; off < 16; off <<= 1) gs += __shfl_xor(gs, off, 64);
        if (l15 == 0) lgsq[m][wv] = gs;
    }
    __syncthreads();

    if (tid < 16) {
        float gsq = 0.f;
        #pragma unroll
        for (int w = 0; w < 16; ++w) gsq += lgsq[tid][w];
        // ||gW||_F^2 + ||gb||^2 = (||x||^2 + 1) * ||g||^2
        out[s0 + tid] = sqrtf((xn2s[tid] + 1.0f) * gsq);
    }
}

extern "C" void kernel_launch(void* const* d_in, const int* in_sizes, int n_in,
                              void* d_out, int out_size, void* d_ws, size_t ws_size,
                              hipStream_t stream) {
    const float* x  = (const float*)d_in[0];
    const float* y  = (const float*)d_in[1];
    const float* W  = (const float*)d_in[2];
    const float* b  = (const float*)d_in[3];
    float* out = (float*)d_out;

    unsigned short* xb = (unsigned short*)d_ws;                         // 1 MB
    unsigned short* wt = (unsigned short*)((char*)d_ws + (size_t)Bn * Dn * 2); // 0.5 MB

    conv_kernel<<<dim3(256 + 64), dim3(256), 0, stream>>>(x, W, xb, wt);
    gnorm_mfma<<<dim3(Bn / 16), dim3(1024), 0, stream>>>(xb, wt, x, y, b, out);
}

// Round 5
// 84.651 us; speedup vs baseline: 1.0514x; 1.0514x over previous
//
#include <hip/hip_runtime.h>

#define Bn 1024
#define Dn 512
#define Cn 512

typedef __attribute__((ext_vector_type(8))) short s16x8;   // 8 bf16 = 4 VGPR (MFMA A/B frag)
typedef __attribute__((ext_vector_type(4))) float f32x4;   // MFMA C/D frag
typedef __attribute__((ext_vector_type(4))) unsigned short u16x4;
typedef __attribute__((ext_vector_type(8))) unsigned short u16x8;

__device__ __forceinline__ unsigned short f2bf(float f) {  // RNE f32->bf16
    unsigned u = __builtin_bit_cast(unsigned, f);
    u += 0x7FFF + ((u >> 16) & 1);
    return (unsigned short)(u >> 16);
}

__device__ __forceinline__ float waveSum(float v) {
    #pragma unroll
    for (int off = 32; off > 0; off >>= 1) v += __shfl_xor(v, off, 64);
    return v;
}

// bid < 256: x fp32 -> bf16 (row-major). bid >= 256: W[k][c] -> Wt[c][k] bf16 via LDS tile.
// (unchanged from R4 — verified correct)
__global__ __launch_bounds__(256) void conv_kernel(const float* __restrict__ x,
                                                   const float* __restrict__ W,
                                                   unsigned short* __restrict__ xb,
                                                   unsigned short* __restrict__ wt)
{
    const int tid = threadIdx.x;
    if (blockIdx.x < 256) {
        const int base = (blockIdx.x * 256 + tid) * 8;
        float4 v0 = *(const float4*)&x[base];
        float4 v1 = *(const float4*)&x[base + 4];
        u16x8 o;
        o[0] = f2bf(v0.x); o[1] = f2bf(v0.y); o[2] = f2bf(v0.z); o[3] = f2bf(v0.w);
        o[4] = f2bf(v1.x); o[5] = f2bf(v1.y); o[6] = f2bf(v1.z); o[7] = f2bf(v1.w);
        *(u16x8*)&xb[base] = o;
    } else {
        __shared__ unsigned short lt[64][73];   // [c_local][k_local], odd pad
        const int tb = blockIdx.x - 256;        // 8x8 tiles of 64x64
        const int k0 = (tb >> 3) * 64, c0 = (tb & 7) * 64;
        const int rr = tid >> 4, cc = tid & 15;
        #pragma unroll
        for (int p = 0; p < 4; ++p) {
            const int kl = rr + p * 16;
            float4 v = *(const float4*)&W[(size_t)(k0 + kl) * Cn + c0 + cc * 4];
            lt[cc * 4 + 0][kl] = f2bf(v.x);
            lt[cc * 4 + 1][kl] = f2bf(v.y);
            lt[cc * 4 + 2][kl] = f2bf(v.z);
            lt[cc * 4 + 3][kl] = f2bf(v.w);
        }
        __syncthreads();
        #pragma unroll
        for (int p = 0; p < 4; ++p) {
            const int cl = rr + p * 16;
            u16x4 o;
            o[0] = lt[cl][cc * 4 + 0]; o[1] = lt[cl][cc * 4 + 1];
            o[2] = lt[cl][cc * 4 + 2]; o[3] = lt[cl][cc * 4 + 3];
            *(u16x4*)&wt[(size_t)(c0 + cl) * Dn + k0 + cc * 4] = o;
        }
    }
}

// grid=64, block=512 (8 waves). Block: 16 samples x full 512 cols.
// Wave wv owns cols [wv*64, wv*64+64) = 4 MFMA col-tiles -> 4 independent acc chains.
__global__ __launch_bounds__(512) void gnorm_mfma(
    const unsigned short* __restrict__ xb,   // [B][D] bf16
    const unsigned short* __restrict__ wt,   // [C][D] bf16 (= W^T)
    const float* __restrict__ x,             // fp32, for ||x||^2
    const float* __restrict__ y,             // [B][C]
    const float* __restrict__ bias,          // [C]
    float* __restrict__ out)                 // [B]
{
    __shared__ float lmax[16][8];
    __shared__ float lsum[16][8];
    __shared__ float lgsq[16][8];
    __shared__ float xn2s[16];

    const int tid = threadIdx.x;
    const int wv  = tid >> 6;        // 0..7
    const int l   = tid & 63;
    const int l15 = l & 15;
    const int lg  = l >> 4;          // 0..3
    const int s0  = blockIdx.x * 16;

    // ---- ||x||^2: wave wv owns rows 2wv, 2wv+1 (fp32, exact) ----
    #pragma unroll
    for (int rr = 0; rr < 2; ++rr) {
        const int row = 2 * wv + rr;
        const float* xr = &x[(size_t)(s0 + row) * Dn + l * 8];
        float4 a = *(const float4*)xr;
        float4 b = *(const float4*)(xr + 4);
        float ss = a.x*a.x + a.y*a.y + a.z*a.z + a.w*a.w
                 + b.x*b.x + b.y*b.y + b.z*b.z + b.w*b.w;
        ss = waveSum(ss);
        if (l == 0) xn2s[row] = ss;
    }

    // ---- GEMM: 16 rows x 64 cols per wave, K=512 in 16 MFMA steps ----
    // A frag: lane holds xb[s0+(l&15)][(l>>4)*8 + j + ks*32]  (16B contiguous)
    // B frag: lane holds wt[c][(l>>4)*8 + j + ks*32]          (16B contiguous)
    f32x4 acc[4];
    #pragma unroll
    for (int t = 0; t < 4; ++t) acc[t] = (f32x4){0.f, 0.f, 0.f, 0.f};

    const unsigned short* ap = &xb[(size_t)(s0 + l15) * Dn + lg * 8];
    const unsigned short* bp[4];
    #pragma unroll
    for (int t = 0; t < 4; ++t)
        bp[t] = &wt[(size_t)(wv * 64 + t * 16 + l15) * Dn + lg * 8];

    #pragma unroll
    for (int ks = 0; ks < 16; ++ks) {
        s16x8 a = *(const s16x8*)(ap + ks * 32);
        #pragma unroll
        for (int t = 0; t < 4; ++t) {
            s16x8 b = *(const s16x8*)(bp[t] + ks * 32);
            acc[t] = __builtin_amdgcn_mfma_f32_16x16x32_bf16(a, b, acc[t], 0, 0, 0);
        }
    }

    // ---- Epilogue. C/D layout: col = l&15 (within tile), row = (l>>4)*4 + reg ----
    float bv[4];
    #pragma unroll
    for (int t = 0; t < 4; ++t) bv[t] = bias[wv * 64 + t * 16 + l15];

    float z[4][4];   // [reg r][tile t]
    #pragma unroll
    for (int r = 0; r < 4; ++r)
        #pragma unroll
        for (int t = 0; t < 4; ++t) z[r][t] = acc[t][r] + bv[t];

    // per-row max over this wave's 64 cols
    #pragma unroll
    for (int r = 0; r < 4; ++r) {
        float vm = fmaxf(fmaxf(z[r][0], z[r][1]), fmaxf(z[r][2], z[r][3]));
        #pragma unroll
        for (int off = 1; off < 16; off <<= 1) vm = fmaxf(vm, __shfl_xor(vm, off, 64));
        if (l15 == 0) lmax[lg * 4 + r][wv] = vm;
    }
    __syncthreads();

    float e[4][4];
    #pragma unroll
    for (int r = 0; r < 4; ++r) {
        const int m = lg * 4 + r;
        float vm = lmax[m][0];
        #pragma unroll
        for (int w = 1; w < 8; ++w) vm = fmaxf(vm, lmax[m][w]);
        float sv = 0.f;
        #pragma unroll
        for (int t = 0; t < 4; ++t) { e[r][t] = __expf(z[r][t] - vm); sv += e[r][t]; }
        #pragma unroll
        for (int off = 1; off < 16; off <<= 1) sv += __shfl_xor(sv, off, 64);
        if (l15 == 0) lsum[m][wv] = sv;
    }
    __syncthreads();

    #pragma unroll
    for (int r = 0; r < 4; ++r) {
        const int m = lg * 4 + r;
        float dv = 0.f;
        #pragma unroll
        for (int w = 0; w < 8; ++w) dv += lsum[m][w];
        const float inv = 1.0f / dv;
        float gs = 0.f;
        #pragma unroll
        for (int t = 0; t < 4; ++t) {
            float g = e[r][t] * inv - y[(size_t)(s0 + m) * Cn + wv * 64 + t * 16 + l15];
            gs += g * g;
        }
        #pragma unroll
        for (int off = 1; off < 16; off <<= 1) gs += __shfl_xor(gs, off, 64);
        if (l15 == 0) lgsq[m][wv] = gs;
    }
    __syncthreads();

    if (tid < 16) {
        float gsq = 0.f;
        #pragma unroll
        for (int w = 0; w < 8; ++w) gsq += lgsq[tid][w];
        // ||gW||_F^2 + ||gb||^2 = (||x||^2 + 1) * ||g||^2
        out[s0 + tid] = sqrtf((xn2s[tid] + 1.0f) * gsq);
    }
}

extern "C" void kernel_launch(void* const* d_in, const int* in_sizes, int n_in,
                              void* d_out, int out_size, void* d_ws, size_t ws_size,
                              hipStream_t stream) {
    const float* x  = (const float*)d_in[0];
    const float* y  = (const float*)d_in[1];
    const float* W  = (const float*)d_in[2];
    const float* b  = (const float*)d_in[3];
    float* out = (float*)d_out;

    unsigned short* xb = (unsigned short*)d_ws;                               // 1 MB
    unsigned short* wt = (unsigned short*)((char*)d_ws + (size_t)Bn * Dn * 2); // 0.5 MB

    conv_kernel<<<dim3(256 + 64), dim3(256), 0, stream>>>(x, W, xb, wt);
    gnorm_mfma<<<dim3(Bn / 16), dim3(512), 0, stream>>>(xb, wt, x, y, b, out);
}

// Round 9
// 75.387 us; speedup vs baseline: 1.1806x; 1.1229x over previous
//
#include <hip/hip_runtime.h>

#define Bn 1024
#define Dn 512
#define Cn 512
#define KT 64           // k per staged B tile
#define NTL (Dn / KT)   // 8 tiles

typedef __attribute__((ext_vector_type(8))) short s16x8;   // MFMA A/B frag (8 bf16)
typedef __attribute__((ext_vector_type(4))) float f32x4;   // MFMA C/D frag
typedef __attribute__((ext_vector_type(4))) unsigned short u16x4;
typedef __attribute__((ext_vector_type(8))) unsigned short u16x8;

__device__ __forceinline__ unsigned short f2bf(float f) {  // RNE f32->bf16
    unsigned u = __builtin_bit_cast(unsigned, f);
    u += 0x7FFF + ((u >> 16) & 1);
    return (unsigned short)(u >> 16);
}

// W[k][c] fp32 -> wt[c][k] bf16 via LDS tile. 64 blocks x 256 thr. (verified R4/R5)
__global__ __launch_bounds__(256) void wconv_kernel(const float* __restrict__ W,
                                                    unsigned short* __restrict__ wt)
{
    __shared__ unsigned short lt[64][73];   // [c_local][k_local], odd pad
    const int tid = threadIdx.x;
    const int tb = blockIdx.x;              // 8x8 tiles of 64x64
    const int k0 = (tb >> 3) * 64, c0 = (tb & 7) * 64;
    const int rr = tid >> 4, cc = tid & 15;
    #pragma unroll
    for (int p = 0; p < 4; ++p) {
        const int kl = rr + p * 16;
        float4 v = *(const float4*)&W[(size_t)(k0 + kl) * Cn + c0 + cc * 4];
        lt[cc * 4 + 0][kl] = f2bf(v.x);
        lt[cc * 4 + 1][kl] = f2bf(v.y);
        lt[cc * 4 + 2][kl] = f2bf(v.z);
        lt[cc * 4 + 3][kl] = f2bf(v.w);
    }
    __syncthreads();
    #pragma unroll
    for (int p = 0; p < 4; ++p) {
        const int cl = rr + p * 16;
        u16x4 o;
        o[0] = lt[cl][cc * 4 + 0]; o[1] = lt[cl][cc * 4 + 1];
        o[2] = lt[cl][cc * 4 + 2]; o[3] = lt[cl][cc * 4 + 3];
        *(u16x4*)&wt[(size_t)(c0 + cl) * Dn + k0 + cc * 4] = o;
    }
}

// grid=64, block=512 (8 waves). Block: 16 samples x full 512 cols.
// A (x->bf16) in 16KB swizzled LDS; B (wt) double-buffered 2x64KB swizzled LDS.
__global__ __launch_bounds__(512) void gnorm_mfma(
    const float* __restrict__ x,             // [B][D] fp32
    const unsigned short* __restrict__ wt,   // [C][D] bf16 (= W^T)
    const float* __restrict__ y,             // [B][C]
    const float* __restrict__ bias,          // [C]
    float* __restrict__ out)                 // [B]
{
    __shared__ unsigned short Ab[16 * 512];        // 16 KB: row r at r*1024B, 16B chunks XOR (r&7)
    __shared__ unsigned short Bb[2 * 512 * KT];    // 2 x 64 KB: row c at c*128B, chunks XOR (c&7)
    __shared__ float lmax[16 * 8], lsum[16 * 8], lgsq[16 * 8], xn2s[16];

    const int tid = threadIdx.x;
    const int wv  = tid >> 6;        // 0..7
    const int l   = tid & 63;
    const int l15 = l & 15;
    const int lg  = l >> 4;          // 0..3
    const int s0  = blockIdx.x * 16;

    // ---- A stage (coalesced fp32 read, fused ||x||^2 + bf16 convert) ----
    {
        const int row = tid >> 5, cs = tid & 31;   // 16 fp32 per thread
        const float* xp = &x[(size_t)(s0 + row) * Dn + cs * 16];
        float4 v0 = *(const float4*)xp,       v1 = *(const float4*)(xp + 4);
        float4 v2 = *(const float4*)(xp + 8), v3 = *(const float4*)(xp + 12);
        float ss = v0.x*v0.x + v0.y*v0.y + v0.z*v0.z + v0.w*v0.w
                 + v1.x*v1.x + v1.y*v1.y + v1.z*v1.z + v1.w*v1.w
                 + v2.x*v2.x + v2.y*v2.y + v2.z*v2.z + v2.w*v2.w
                 + v3.x*v3.x + v3.y*v3.y + v3.z*v3.z + v3.w*v3.w;
        u16x8 o0, o1;
        o0[0]=f2bf(v0.x); o0[1]=f2bf(v0.y); o0[2]=f2bf(v0.z); o0[3]=f2bf(v0.w);
        o0[4]=f2bf(v1.x); o0[5]=f2bf(v1.y); o0[6]=f2bf(v1.z); o0[7]=f2bf(v1.w);
        o1[0]=f2bf(v2.x); o1[1]=f2bf(v2.y); o1[2]=f2bf(v2.z); o1[3]=f2bf(v2.w);
        o1[4]=f2bf(v3.x); o1[5]=f2bf(v3.y); o1[6]=f2bf(v3.z); o1[7]=f2bf(v3.w);
        char* base = (char*)Ab + row * 1024;
        *(u16x8*)(base + (((2*cs    ) ^ (row & 7)) << 4)) = o0;
        *(u16x8*)(base + (((2*cs + 1) ^ (row & 7)) << 4)) = o1;
        #pragma unroll
        for (int off = 1; off < 32; off <<= 1) ss += __shfl_xor(ss, off, 32);
        if ((tid & 31) == 0) xn2s[row] = ss;
    }

    // ---- B staging helper: tile kt -> buffer b (contiguous 16B global, swizzled LDS) ----
    const int bc = (wv * 8) * 8 + (l >> 3);   // base c for this wave's instr 0
    const int kc = l & 7;                     // 16B chunk within 128B tile-row
    const int swz = (kc ^ (l >> 3)) << 4;     // (c&7) == l>>3 here
#define STAGE_B(kt_, b_)                                                        \
    {                                                                           \
        _Pragma("unroll")                                                       \
        for (int i = 0; i < 8; ++i) {                                           \
            const int c = bc + i * 8;                                           \
            u16x8 v = *(const u16x8*)&wt[(size_t)c * Dn + (kt_) * KT + kc * 8]; \
            *(u16x8*)((char*)Bb + (b_) * (512 * KT * 2) + c * 128 + swz) = v;   \
        }                                                                       \
    }

    STAGE_B(0, 0);
    __syncthreads();

    // ---- K-loop: 8 tiles, double-buffered, single barrier per tile ----
    f32x4 acc[4];
    #pragma unroll
    for (int t = 0; t < 4; ++t) acc[t] = (f32x4){0.f, 0.f, 0.f, 0.f};

    for (int kt = 0; kt < NTL; ++kt) {
        if (kt + 1 < NTL) STAGE_B(kt + 1, (kt + 1) & 1);
        const char* bbase = (const char*)Bb + (kt & 1) * (512 * KT * 2);
        #pragma unroll
        for (int ksl = 0; ksl < 2; ++ksl) {
            const int ks = kt * 2 + ksl;
            s16x8 a = *(const s16x8*)((char*)Ab + l15 * 1024 +
                                      (((lg + ks * 4) ^ (l15 & 7)) << 4));
            #pragma unroll
            for (int t = 0; t < 4; ++t) {
                const int c = wv * 64 + t * 16 + l15;   // c&7 == l15&7
                s16x8 bf = *(const s16x8*)(bbase + c * 128 +
                                           (((lg + ksl * 4) ^ (l15 & 7)) << 4));
                acc[t] = __builtin_amdgcn_mfma_f32_16x16x32_bf16(a, bf, acc[t], 0, 0, 0);
            }
        }
        __syncthreads();
    }

    // ---- Epilogue (verified R5). C/D: col = l15 (within tile), row = lg*4 + r ----
    float bv[4];
    #pragma unroll
    for (int t = 0; t < 4; ++t) bv[t] = bias[wv * 64 + t * 16 + l15];
    float z[4][4];
    #pragma unroll
    for (int r = 0; r < 4; ++r)
        #pragma unroll
        for (int t = 0; t < 4; ++t) z[r][t] = acc[t][r] + bv[t];

    #pragma unroll
    for (int r = 0; r < 4; ++r) {
        float vm = fmaxf(fmaxf(z[r][0], z[r][1]), fmaxf(z[r][2], z[r][3]));
        #pragma unroll
        for (int off = 1; off < 16; off <<= 1) vm = fmaxf(vm, __shfl_xor(vm, off, 64));
        if (l15 == 0) lmax[(lg * 4 + r) * 8 + wv] = vm;
    }
    __syncthreads();

    float e[4][4];
    #pragma unroll
    for (int r = 0; r < 4; ++r) {
        const int m = lg * 4 + r;
        float vm = lmax[m * 8];
        #pragma unroll
        for (int w = 1; w < 8; ++w) vm = fmaxf(vm, lmax[m * 8 + w]);
        float sv = 0.f;
        #pragma unroll
        for (int t = 0; t < 4; ++t) { e[r][t] = __expf(z[r][t] - vm); sv += e[r][t]; }
        #pragma unroll
        for (int off = 1; off < 16; off <<= 1) sv += __shfl_xor(sv, off, 64);
        if (l15 == 0) lsum[m * 8 + wv] = sv;
    }
    __syncthreads();

    #pragma unroll
    for (int r = 0; r < 4; ++r) {
        const int m = lg * 4 + r;
        float dv = 0.f;
        #pragma unroll
        for (int w = 0; w < 8; ++w) dv += lsum[m * 8 + w];
        const float inv = 1.0f / dv;
        float gs = 0.f;
        #pragma unroll
        for (int t = 0; t < 4; ++t) {
            float g = e[r][t] * inv - y[(size_t)(s0 + m) * Cn + wv * 64 + t * 16 + l15];
            gs += g * g;
        }
        #pragma unroll
        for (int off = 1; off < 16; off <<= 1) gs += __shfl_xor(gs, off, 64);
        if (l15 == 0) lgsq[m * 8 + wv] = gs;
    }
    __syncthreads();

    if (tid < 16) {
        float gsq = 0.f;
        #pragma unroll
        for (int w = 0; w < 8; ++w) gsq += lgsq[tid * 8 + w];
        // ||gW||_F^2 + ||gb||^2 = (||x||^2 + 1) * ||g||^2
        out[s0 + tid] = sqrtf((xn2s[tid] + 1.0f) * gsq);
    }
}

extern "C" void kernel_launch(void* const* d_in, const int* in_sizes, int n_in,
                              void* d_out, int out_size, void* d_ws, size_t ws_size,
                              hipStream_t stream) {
    const float* x  = (const float*)d_in[0];
    const float* y  = (const float*)d_in[1];
    const float* W  = (const float*)d_in[2];
    const float* b  = (const float*)d_in[3];
    float* out = (float*)d_out;

    unsigned short* wt = (unsigned short*)d_ws;   // 512 KB bf16 W^T

    wconv_kernel<<<dim3(64), dim3(256), 0, stream>>>(W, wt);
    gnorm_mfma<<<dim3(Bn / 16), dim3(512), 0, stream>>>(x, wt, y, b, out);
}